// Round 5
// baseline (295.168 us; speedup 1.0000x reference)
//
#include <hip/hip_runtime.h>
#include <math.h>
#include <stdint.h>

#define B_ROWS 2048
#define D_DIM  512
#define V_COLS 32000
#define BM 128
#define BN 128
#define BK 64
#define KSTEPS (D_DIM / BK)             // 8
#define NCT    (V_COLS / BN)            // 250 col tiles
#define S_SC   30.0f
#define COS_M  0.8775825618903728f      // cos(0.5)
#define SIN_M  0.479425538604203f       // sin(0.5)

typedef float f32x16 __attribute__((ext_vector_type(16)));
typedef int   i32x4v __attribute__((ext_vector_type(4)));
typedef int   i32x8v __attribute__((ext_vector_type(8)));

__device__ __forceinline__ void load16_to_lds(const void* g, void* l) {
  __builtin_amdgcn_global_load_lds(
      (__attribute__((address_space(1))) void*)(g),
      (__attribute__((address_space(3))) void*)(l),
      16, 0, 0);
}

// ---------- kernel 1: fused row L2-normalize (x,W) fp32 -> fp8 e4m3, + zero rowsum/out ----------
__global__ void fused_norm_kernel(const float* __restrict__ x,
                                  const float* __restrict__ W,
                                  uint8_t* __restrict__ nx,
                                  uint8_t* __restrict__ nw,
                                  float* __restrict__ rowsum,
                                  float* __restrict__ out) {
  if (blockIdx.x == 0 && threadIdx.x == 0) out[0] = 0.f;
  if (blockIdx.x < B_ROWS / 256) rowsum[blockIdx.x * 256 + threadIdx.x] = 0.f;
  const int lane = threadIdx.x & 63;
  const int wave = threadIdx.x >> 6;
  const int gr   = blockIdx.x * 4 + wave;
  const float* src;
  uint8_t* dst;
  if (gr < B_ROWS) {
    src = x + (size_t)gr * D_DIM;
    dst = nx + (size_t)gr * D_DIM;
  } else {
    src = W + (size_t)(gr - B_ROWS) * D_DIM;
    dst = nw + (size_t)(gr - B_ROWS) * D_DIM;
  }
  const float4* r4 = (const float4*)src;
  float4 v0 = r4[2 * lane];
  float4 v1 = r4[2 * lane + 1];
  float ss = v0.x*v0.x + v0.y*v0.y + v0.z*v0.z + v0.w*v0.w
           + v1.x*v1.x + v1.y*v1.y + v1.z*v1.z + v1.w*v1.w;
  #pragma unroll
  for (int off = 32; off >= 1; off >>= 1) ss += __shfl_xor(ss, off, 64);
  float inv = 1.0f / fmaxf(sqrtf(ss), 1e-12f);
  int p0 = __builtin_amdgcn_cvt_pk_fp8_f32(v0.x * inv, v0.y * inv, 0, false);
  p0     = __builtin_amdgcn_cvt_pk_fp8_f32(v0.z * inv, v0.w * inv, p0, true);
  int p1 = __builtin_amdgcn_cvt_pk_fp8_f32(v1.x * inv, v1.y * inv, 0, false);
  p1     = __builtin_amdgcn_cvt_pk_fp8_f32(v1.z * inv, v1.w * inv, p1, true);
  ((int2*)dst)[lane] = make_int2(p0, p1);
}

// ---------- kernel 2: fp8 GEMM via MX-scaled 32x32x64 f8f6f4 MFMA (unit scales) ----------
// R15: R1-R4 falsified all schedule-structure levers (counted vmcnt / phase split /
// fusion all <= R0's 87 us @ 31% MfmaUtil; inter-block overlap at 3 blocks/CU already
// hides the barrier drain, m114). New lever reduces MFMA-PIPE WORK instead:
// mfma_scale_f32_32x32x64_f8f6f4 runs at ~2x the non-scaled fp8 rate (m148: 1.64x
// end-to-end on this structure class). With all E8M0 scales = 127 (2^0 = 1.0) the
// result is the bit-identical fp8 dot product. MFMA per wave-K-step: 32 -> 4.
// Everything else is the byte-identical R0 87-us structure (2-buffer syncthreads loop,
// staging involution, grid, fixed-shift softmax epilogue).
// Frag math: lane (h = l>>5, c = l&31) needs canonical 16B chunks {2h, 2h+1} of its
// row/col. LDS slot s of row r holds chunk s ^ ((r>>1)&3) (R0 staging); swz =
// (c>>1)&3 is bi-invariant (32*bi = 0 mod 8). Chunk 2h at row*64 + ((2h^swz)<<4),
// chunk 2h+1 at that addr ^ 16. Per-8-lane bank-group audit: distinct -> 0 conflicts.
// C/D layout 32x32: col = lane&31, row = (g&3) + 8*(g>>2) + 4*h (shape-determined,
// dtype-independent: m74/m101/m127/m128).
__global__ __launch_bounds__(256, 3)
void arc_gemm_kernel(const uint8_t* __restrict__ nx,
                     const uint8_t* __restrict__ nw,
                     const int* __restrict__ labels,
                     float* __restrict__ rowsum,
                     float* __restrict__ lbl_logit) {
  __shared__ uint8_t sA[2][BM * BK];   // 2 x 8 KB
  __shared__ uint8_t sB[2][BN * BK];   // 2 x 8 KB

  const int id = blockIdx.x;
  const int ct = ((id >> 7) << 3) | (id & 7);
  if (ct >= NCT) return;
  const int rt = (id >> 3) & 15;
  const int m0 = rt * BM;
  const int n0 = ct * BN;

  const int tid  = threadIdx.x;
  const int wave = tid >> 6;
  const int lane = tid & 63;
  const int wm   = wave >> 1;
  const int wn   = wave & 1;
  const int c31  = lane & 31;
  const int h    = lane >> 5;

  // staging: inst i covers rows i*64 + (tid>>2); slot tid&3 <- global 16B chunk jg.
  const int srow = tid >> 2;
  const int jg   = (tid & 3) ^ ((srow >> 1) & 3);
  const uint8_t* gA = nx + (size_t)(m0 + srow) * D_DIM + jg * 16;
  const uint8_t* gB = nw + (size_t)(n0 + srow) * D_DIM + jg * 16;
  const int ldsOff0 = wave * 1024;          // wave-uniform LDS byte bases
  const int ldsOff1 = 4096 + wave * 1024;

  // frag read bases: chunk 2h of row (wm*64 + bi*32 + c31); pair partner = addr ^ 16
  const int swz  = (c31 >> 1) & 3;
  const int s0   = ((2 * h) ^ swz) << 4;
  const int aA0  = (wm * 64 + c31) * BK + s0;   // bi=1: + 32*BK
  const int bB0  = (wn * 64 + c31) * BK + s0;   // bj=1: + 32*BK

  f32x16 acc[2][2];
  #pragma unroll
  for (int i = 0; i < 2; ++i)
    #pragma unroll
    for (int j = 0; j < 2; ++j)
      #pragma unroll
      for (int g = 0; g < 16; ++g) acc[i][j][g] = 0.f;

  // prologue: tile 0 -> buf 0
  load16_to_lds(gA,              &sA[0][ldsOff0]);
  load16_to_lds(gA + 64 * D_DIM, &sA[0][ldsOff1]);
  load16_to_lds(gB,              &sB[0][ldsOff0]);
  load16_to_lds(gB + 64 * D_DIM, &sB[0][ldsOff1]);

  #pragma unroll
  for (int ks = 0; ks < KSTEPS; ++ks) {
    __syncthreads();                          // prev compute done before overwrite
    if (ks + 1 < KSTEPS) {
      const int off = (ks + 1) * BK;
      const int nb  = (ks + 1) & 1;
      load16_to_lds(gA + off,              &sA[nb][ldsOff0]);
      load16_to_lds(gA + 64 * D_DIM + off, &sA[nb][ldsOff1]);
      load16_to_lds(gB + off,              &sB[nb][ldsOff0]);
      load16_to_lds(gB + 64 * D_DIM + off, &sB[nb][ldsOff1]);
    }
    __syncthreads();                          // tile ks resident

    const uint8_t* bA = sA[ks & 1];
    const uint8_t* bB = sB[ks & 1];

    i32x4v a0l = *(const i32x4v*)(bA + aA0);
    i32x4v a0h = *(const i32x4v*)(bA + (aA0 ^ 16));
    i32x4v a1l = *(const i32x4v*)(bA + aA0 + 32 * BK);
    i32x4v a1h = *(const i32x4v*)(bA + ((aA0 + 32 * BK) ^ 16));
    i32x4v b0l = *(const i32x4v*)(bB + bB0);
    i32x4v b0h = *(const i32x4v*)(bB + (bB0 ^ 16));
    i32x4v b1l = *(const i32x4v*)(bB + bB0 + 32 * BK);
    i32x4v b1h = *(const i32x4v*)(bB + ((bB0 + 32 * BK) ^ 16));
    i32x8v aF0 = __builtin_shufflevector(a0l, a0h, 0, 1, 2, 3, 4, 5, 6, 7);
    i32x8v aF1 = __builtin_shufflevector(a1l, a1h, 0, 1, 2, 3, 4, 5, 6, 7);
    i32x8v bF0 = __builtin_shufflevector(b0l, b0h, 0, 1, 2, 3, 4, 5, 6, 7);
    i32x8v bF1 = __builtin_shufflevector(b1l, b1h, 0, 1, 2, 3, 4, 5, 6, 7);

    // unit scales: E8M0 byte 127 = 2^0; fmt 0 = fp8 e4m3 for both operands
    acc[0][0] = __builtin_amdgcn_mfma_scale_f32_32x32x64_f8f6f4(aF0, bF0, acc[0][0], 0, 0, 0, 127, 0, 127);
    acc[0][1] = __builtin_amdgcn_mfma_scale_f32_32x32x64_f8f6f4(aF0, bF1, acc[0][1], 0, 0, 0, 127, 0, 127);
    acc[1][0] = __builtin_amdgcn_mfma_scale_f32_32x32x64_f8f6f4(aF1, bF0, acc[1][0], 0, 0, 0, 127, 0, 127);
    acc[1][1] = __builtin_amdgcn_mfma_scale_f32_32x32x64_f8f6f4(aF1, bF1, acc[1][1], 0, 0, 0, 127, 0, 127);
  }

  // Epilogue. 32x32 C/D layout: col = c31, row = (g&3) + 8*(g>>2) + 4*h.
  const int lblv = labels[m0 + wm * 64 + lane];
  #pragma unroll
  for (int bi = 0; bi < 2; ++bi) {
    #pragma unroll
    for (int g = 0; g < 16; ++g) {
      const int rr   = (g & 3) + ((g >> 2) << 3) + (h << 2);   // 0..31
      const int grow = m0 + wm * 64 + bi * 32 + rr;
      const int lbl  = __shfl(lblv, bi * 32 + rr, 64);
      float rsum = 0.f;
      #pragma unroll
      for (int bj = 0; bj < 2; ++bj) {
        float c = acc[bi][bj][g];
        const int gcol = n0 + wn * 64 + bj * 32 + c31;
        if (gcol == lbl) {
          float sy  = sqrtf(fminf(1.f, fmaxf(0.f, 1.f - c * c)));
          float phi = c * COS_M - sy * SIN_M;
          lbl_logit[grow] = S_SC * phi;       // exactly one lane grid-wide
          c = phi;
        }
        rsum += __expf(S_SC * c - 30.0f);     // fixed shift: logits in [-30,30]
      }
      #pragma unroll
      for (int off = 1; off < 32; off <<= 1)
        rsum += __shfl_xor(rsum, off, 64);    // reduce within 32-lane half (rows differ by h)
      if (c31 == 0) atomicAdd(&rowsum[grow], rsum);
    }
  }
}

// ---------- kernel 3: per-row loss + global mean ----------
__global__ void arc_finish_kernel(const float* __restrict__ rowsum,
                                  const float* __restrict__ lbl_logit,
                                  float* __restrict__ out) {
  const int row  = blockIdx.x * 256 + threadIdx.x;   // 8 blocks x 256
  const int lane = threadIdx.x & 63;
  const int wave = threadIdx.x >> 6;
  float v = (30.0f + logf(rowsum[row]) - lbl_logit[row]) * (1.0f / (float)B_ROWS);
  #pragma unroll
  for (int off = 32; off >= 1; off >>= 1) v += __shfl_xor(v, off, 64);
  __shared__ float wsum[4];
  if (lane == 0) wsum[wave] = v;
  __syncthreads();
  if (threadIdx.x == 0) atomicAdd(out, wsum[0] + wsum[1] + wsum[2] + wsum[3]);
}

// ---------- launch ----------
extern "C" void kernel_launch(void* const* d_in, const int* in_sizes, int n_in,
                              void* d_out, int out_size, void* d_ws, size_t ws_size,
                              hipStream_t stream) {
  const float* x      = (const float*)d_in[0];
  const float* W      = (const float*)d_in[1];
  const int*   labels = (const int*)d_in[2];
  float* out = (float*)d_out;

  char* ws = (char*)d_ws;
  uint8_t* nx = (uint8_t*)ws;                                       // 1 MB
  uint8_t* nw = (uint8_t*)(ws + (size_t)B_ROWS * D_DIM);            // 16.4 MB
  char* p = ws + (size_t)B_ROWS * D_DIM + (size_t)V_COLS * D_DIM;
  float* rowsum    = (float*)p;  p += (size_t)B_ROWS * 4;           // 8 KB
  float* lbl_logit = (float*)p;                                     // 8 KB

  hipLaunchKernelGGL(fused_norm_kernel, dim3((B_ROWS + V_COLS) / 4), dim3(256), 0, stream,
                     x, W, nx, nw, rowsum, out);
  hipLaunchKernelGGL(arc_gemm_kernel, dim3(32 * 16 * 8), dim3(256), 0, stream,
                     nx, nw, labels, rowsum, lbl_logit);
  hipLaunchKernelGGL(arc_finish_kernel, dim3(B_ROWS / 256), dim3(256), 0, stream,
                     rowsum, lbl_logit, out);
}

// Round 6
// 250.920 us; speedup vs baseline: 1.1763x; 1.1763x over previous
//
#include <hip/hip_runtime.h>
#include <math.h>
#include <stdint.h>

#define B_ROWS 2048
#define D_DIM  512
#define V_COLS 32000
#define BM 128
#define BN 128
#define BK 64
#define KSTEPS (D_DIM / BK)             // 8
#define NCT    (V_COLS / BN)            // 250 col tiles
#define S_SC   30.0f
#define COS_M  0.8775825618903728f      // cos(0.5)
#define SIN_M  0.479425538604203f       // sin(0.5)

typedef float f32x16 __attribute__((ext_vector_type(16)));
typedef int   i32x4v __attribute__((ext_vector_type(4)));
typedef int   i32x8v __attribute__((ext_vector_type(8)));

__device__ __forceinline__ void load16_to_lds(const void* g, void* l) {
  __builtin_amdgcn_global_load_lds(
      (__attribute__((address_space(1))) void*)(g),
      (__attribute__((address_space(3))) void*)(l),
      16, 0, 0);
}

// ---------- kernel 1: fused row L2-normalize (x,W) fp32 -> fp8 e4m3, + zero rowsum/out ----------
__global__ void fused_norm_kernel(const float* __restrict__ x,
                                  const float* __restrict__ W,
                                  uint8_t* __restrict__ nx,
                                  uint8_t* __restrict__ nw,
                                  float* __restrict__ rowsum,
                                  float* __restrict__ out) {
  if (blockIdx.x == 0 && threadIdx.x == 0) out[0] = 0.f;
  if (blockIdx.x < B_ROWS / 256) rowsum[blockIdx.x * 256 + threadIdx.x] = 0.f;
  const int lane = threadIdx.x & 63;
  const int wave = threadIdx.x >> 6;
  const int gr   = blockIdx.x * 4 + wave;
  const float* src;
  uint8_t* dst;
  if (gr < B_ROWS) {
    src = x + (size_t)gr * D_DIM;
    dst = nx + (size_t)gr * D_DIM;
  } else {
    src = W + (size_t)(gr - B_ROWS) * D_DIM;
    dst = nw + (size_t)(gr - B_ROWS) * D_DIM;
  }
  const float4* r4 = (const float4*)src;
  float4 v0 = r4[2 * lane];
  float4 v1 = r4[2 * lane + 1];
  float ss = v0.x*v0.x + v0.y*v0.y + v0.z*v0.z + v0.w*v0.w
           + v1.x*v1.x + v1.y*v1.y + v1.z*v1.z + v1.w*v1.w;
  #pragma unroll
  for (int off = 32; off >= 1; off >>= 1) ss += __shfl_xor(ss, off, 64);
  float inv = 1.0f / fmaxf(sqrtf(ss), 1e-12f);
  int p0 = __builtin_amdgcn_cvt_pk_fp8_f32(v0.x * inv, v0.y * inv, 0, false);
  p0     = __builtin_amdgcn_cvt_pk_fp8_f32(v0.z * inv, v0.w * inv, p0, true);
  int p1 = __builtin_amdgcn_cvt_pk_fp8_f32(v1.x * inv, v1.y * inv, 0, false);
  p1     = __builtin_amdgcn_cvt_pk_fp8_f32(v1.z * inv, v1.w * inv, p1, true);
  ((int2*)dst)[lane] = make_int2(p0, p1);
}

// ---------- kernel 2: fp8 GEMM via MX-scaled 32x32x64 f8f6f4 MFMA (unit scales) ----------
// R16: R5 proved the MX math (absmax 0.0) but spilled the f32x16 acc[2][2] array to
// scratch (FETCH 239 MB / WRITE 412 MB, VGPR_Count 84 -- impossible to hold 64-float
// acc in 84 regs). Fix is codegen-only:
//   * NAMED accumulators c00/c01/c10/c11 (no arrays of ext_vectors, rule #20)
//   * __launch_bounds__(256, 2): unified-reg cap 256 instead of 170
// Math/structure byte-identical to R5 (= R0 2-buffer loop + 32x32x64 scaled MFMA):
// unit E8M0 scales (127 = 2^0) make the scaled op the exact fp8 dot product; MFMA
// instrs per wave-K-step 32 -> 4 at ~2x the per-FLOP rate (m148 precedent 1.64x).
// Frag math (R5-verified): lane (h=l>>5, c=l&31) reads canonical 16B chunks {2h,2h+1}
// of row base+c via the staging involution slot = chunk ^ ((row>>1)&3); swz=(c>>1)&3;
// chunk 2h at row*64 + ((2h^swz)<<4), partner at ^16. Per-8-lane bank audit: distinct.
// C/D 32x32 layout: col = c31, row = (g&3) + 8*(g>>2) + 4*h (m74/m101, dtype-indep).
__global__ __launch_bounds__(256, 2)
void arc_gemm_kernel(const uint8_t* __restrict__ nx,
                     const uint8_t* __restrict__ nw,
                     const int* __restrict__ labels,
                     float* __restrict__ rowsum,
                     float* __restrict__ lbl_logit) {
  __shared__ uint8_t sA[2][BM * BK];   // 2 x 8 KB
  __shared__ uint8_t sB[2][BN * BK];   // 2 x 8 KB

  const int id = blockIdx.x;
  const int ct = ((id >> 7) << 3) | (id & 7);
  if (ct >= NCT) return;
  const int rt = (id >> 3) & 15;
  const int m0 = rt * BM;
  const int n0 = ct * BN;

  const int tid  = threadIdx.x;
  const int wave = tid >> 6;
  const int lane = tid & 63;
  const int wm   = wave >> 1;
  const int wn   = wave & 1;
  const int c31  = lane & 31;
  const int h    = lane >> 5;

  // staging: inst i covers rows i*64 + (tid>>2); slot tid&3 <- global 16B chunk jg.
  const int srow = tid >> 2;
  const int jg   = (tid & 3) ^ ((srow >> 1) & 3);
  const uint8_t* gA = nx + (size_t)(m0 + srow) * D_DIM + jg * 16;
  const uint8_t* gB = nw + (size_t)(n0 + srow) * D_DIM + jg * 16;
  const int ldsOff0 = wave * 1024;          // wave-uniform LDS byte bases
  const int ldsOff1 = 4096 + wave * 1024;

  // frag read bases: chunk 2h of row (wm*64 + bi*32 + c31); pair partner = addr ^ 16
  const int swz  = (c31 >> 1) & 3;
  const int s0   = ((2 * h) ^ swz) << 4;
  const int aA0  = (wm * 64 + c31) * BK + s0;   // bi=1: + 32*BK
  const int bB0  = (wn * 64 + c31) * BK + s0;   // bj=1: + 32*BK

  f32x16 c00 = {}, c01 = {}, c10 = {}, c11 = {};

  // prologue: tile 0 -> buf 0
  load16_to_lds(gA,              &sA[0][ldsOff0]);
  load16_to_lds(gA + 64 * D_DIM, &sA[0][ldsOff1]);
  load16_to_lds(gB,              &sB[0][ldsOff0]);
  load16_to_lds(gB + 64 * D_DIM, &sB[0][ldsOff1]);

  #pragma unroll
  for (int ks = 0; ks < KSTEPS; ++ks) {
    __syncthreads();                          // prev compute done before overwrite
    if (ks + 1 < KSTEPS) {
      const int off = (ks + 1) * BK;
      const int nb  = (ks + 1) & 1;
      load16_to_lds(gA + off,              &sA[nb][ldsOff0]);
      load16_to_lds(gA + 64 * D_DIM + off, &sA[nb][ldsOff1]);
      load16_to_lds(gB + off,              &sB[nb][ldsOff0]);
      load16_to_lds(gB + 64 * D_DIM + off, &sB[nb][ldsOff1]);
    }
    __syncthreads();                          // tile ks resident

    const uint8_t* bA = sA[ks & 1];
    const uint8_t* bB = sB[ks & 1];

    i32x4v a0l = *(const i32x4v*)(bA + aA0);
    i32x4v a0h = *(const i32x4v*)(bA + (aA0 ^ 16));
    i32x4v a1l = *(const i32x4v*)(bA + aA0 + 32 * BK);
    i32x4v a1h = *(const i32x4v*)(bA + ((aA0 + 32 * BK) ^ 16));
    i32x4v b0l = *(const i32x4v*)(bB + bB0);
    i32x4v b0h = *(const i32x4v*)(bB + (bB0 ^ 16));
    i32x4v b1l = *(const i32x4v*)(bB + bB0 + 32 * BK);
    i32x4v b1h = *(const i32x4v*)(bB + ((bB0 + 32 * BK) ^ 16));
    i32x8v aF0 = __builtin_shufflevector(a0l, a0h, 0, 1, 2, 3, 4, 5, 6, 7);
    i32x8v aF1 = __builtin_shufflevector(a1l, a1h, 0, 1, 2, 3, 4, 5, 6, 7);
    i32x8v bF0 = __builtin_shufflevector(b0l, b0h, 0, 1, 2, 3, 4, 5, 6, 7);
    i32x8v bF1 = __builtin_shufflevector(b1l, b1h, 0, 1, 2, 3, 4, 5, 6, 7);

    // unit scales: E8M0 byte 127 = 2^0; fmt 0 = fp8 e4m3 for both operands
    c00 = __builtin_amdgcn_mfma_scale_f32_32x32x64_f8f6f4(aF0, bF0, c00, 0, 0, 0, 127, 0, 127);
    c01 = __builtin_amdgcn_mfma_scale_f32_32x32x64_f8f6f4(aF0, bF1, c01, 0, 0, 0, 127, 0, 127);
    c10 = __builtin_amdgcn_mfma_scale_f32_32x32x64_f8f6f4(aF1, bF0, c10, 0, 0, 0, 127, 0, 127);
    c11 = __builtin_amdgcn_mfma_scale_f32_32x32x64_f8f6f4(aF1, bF1, c11, 0, 0, 0, 127, 0, 127);
  }

  // Epilogue. 32x32 C/D layout: col = c31, row = (g&3) + 8*(g>>2) + 4*h.
  const int lblv = labels[m0 + wm * 64 + lane];

#define EPI_BLOCK(CA, CB, bi) do {                                             \
    _Pragma("unroll")                                                          \
    for (int g = 0; g < 16; ++g) {                                             \
      const int rr   = (g & 3) + ((g >> 2) << 3) + (h << 2);                   \
      const int grow = m0 + wm * 64 + (bi) * 32 + rr;                          \
      const int lbl  = __shfl(lblv, (bi) * 32 + rr, 64);                       \
      float rsum = 0.f;                                                        \
      {                                                                        \
        float c = CA[g];                                                       \
        const int gcol = n0 + wn * 64 + c31;                                   \
        if (gcol == lbl) {                                                     \
          float sy  = sqrtf(fminf(1.f, fmaxf(0.f, 1.f - c * c)));              \
          float phi = c * COS_M - sy * SIN_M;                                  \
          lbl_logit[grow] = S_SC * phi;                                        \
          c = phi;                                                             \
        }                                                                      \
        rsum += __expf(S_SC * c - 30.0f);                                      \
      }                                                                        \
      {                                                                        \
        float c = CB[g];                                                       \
        const int gcol = n0 + wn * 64 + 32 + c31;                              \
        if (gcol == lbl) {                                                     \
          float sy  = sqrtf(fminf(1.f, fmaxf(0.f, 1.f - c * c)));              \
          float phi = c * COS_M - sy * SIN_M;                                  \
          lbl_logit[grow] = S_SC * phi;                                        \
          c = phi;                                                             \
        }                                                                      \
        rsum += __expf(S_SC * c - 30.0f);                                      \
      }                                                                        \
      _Pragma("unroll")                                                        \
      for (int off = 1; off < 32; off <<= 1)                                   \
        rsum += __shfl_xor(rsum, off, 64);   /* reduce 32-lane half (same h) */ \
      if (c31 == 0) atomicAdd(&rowsum[grow], rsum);                            \
    }                                                                          \
  } while (0)

  EPI_BLOCK(c00, c01, 0);
  EPI_BLOCK(c10, c11, 1);
#undef EPI_BLOCK
}

// ---------- kernel 3: per-row loss + global mean ----------
__global__ void arc_finish_kernel(const float* __restrict__ rowsum,
                                  const float* __restrict__ lbl_logit,
                                  float* __restrict__ out) {
  const int row  = blockIdx.x * 256 + threadIdx.x;   // 8 blocks x 256
  const int lane = threadIdx.x & 63;
  const int wave = threadIdx.x >> 6;
  float v = (30.0f + logf(rowsum[row]) - lbl_logit[row]) * (1.0f / (float)B_ROWS);
  #pragma unroll
  for (int off = 32; off >= 1; off >>= 1) v += __shfl_xor(v, off, 64);
  __shared__ float wsum[4];
  if (lane == 0) wsum[wave] = v;
  __syncthreads();
  if (threadIdx.x == 0) atomicAdd(out, wsum[0] + wsum[1] + wsum[2] + wsum[3]);
}

// ---------- launch ----------
extern "C" void kernel_launch(void* const* d_in, const int* in_sizes, int n_in,
                              void* d_out, int out_size, void* d_ws, size_t ws_size,
                              hipStream_t stream) {
  const float* x      = (const float*)d_in[0];
  const float* W      = (const float*)d_in[1];
  const int*   labels = (const int*)d_in[2];
  float* out = (float*)d_out;

  char* ws = (char*)d_ws;
  uint8_t* nx = (uint8_t*)ws;                                       // 1 MB
  uint8_t* nw = (uint8_t*)(ws + (size_t)B_ROWS * D_DIM);            // 16.4 MB
  char* p = ws + (size_t)B_ROWS * D_DIM + (size_t)V_COLS * D_DIM;
  float* rowsum    = (float*)p;  p += (size_t)B_ROWS * 4;           // 8 KB
  float* lbl_logit = (float*)p;                                     // 8 KB

  hipLaunchKernelGGL(fused_norm_kernel, dim3((B_ROWS + V_COLS) / 4), dim3(256), 0, stream,
                     x, W, nx, nw, rowsum, out);
  hipLaunchKernelGGL(arc_gemm_kernel, dim3(32 * 16 * 8), dim3(256), 0, stream,
                     nx, nw, labels, rowsum, lbl_logit);
  hipLaunchKernelGGL(arc_finish_kernel, dim3(B_ROWS / 256), dim3(256), 0, stream,
                     rowsum, lbl_logit, out);
}

// Round 7
// 176.968 us; speedup vs baseline: 1.6679x; 1.4179x over previous
//
#include <hip/hip_runtime.h>
#include <math.h>
#include <stdint.h>

#define B_ROWS 2048
#define D_DIM  512
#define V_COLS 32000
#define BM 128
#define BN 128
#define BK 64
#define KSTEPS (D_DIM / BK)             // 8
#define NCT    (V_COLS / BN)            // 250 col tiles
#define S_SC   30.0f
#define COS_M  0.8775825618903728f      // cos(0.5)
#define SIN_M  0.479425538604203f       // sin(0.5)

typedef float f32x4 __attribute__((ext_vector_type(4)));
typedef long  i64x2 __attribute__((ext_vector_type(2)));

__device__ __forceinline__ void load16_to_lds(const void* g, void* l) {
  __builtin_amdgcn_global_load_lds(
      (__attribute__((address_space(1))) void*)(g),
      (__attribute__((address_space(3))) void*)(l),
      16, 0, 0);
}

// ---------- kernel 1: fused row L2-normalize (x,W) fp32 -> fp8 e4m3, + zero out ----------
__global__ void fused_norm_kernel(const float* __restrict__ x,
                                  const float* __restrict__ W,
                                  uint8_t* __restrict__ nx,
                                  uint8_t* __restrict__ nw,
                                  float* __restrict__ out) {
  if (blockIdx.x == 0 && threadIdx.x == 0) out[0] = 0.f;
  const int lane = threadIdx.x & 63;
  const int wave = threadIdx.x >> 6;
  const int gr   = blockIdx.x * 4 + wave;
  const float* src;
  uint8_t* dst;
  if (gr < B_ROWS) {
    src = x + (size_t)gr * D_DIM;
    dst = nx + (size_t)gr * D_DIM;
  } else {
    src = W + (size_t)(gr - B_ROWS) * D_DIM;
    dst = nw + (size_t)(gr - B_ROWS) * D_DIM;
  }
  const float4* r4 = (const float4*)src;
  float4 v0 = r4[2 * lane];
  float4 v1 = r4[2 * lane + 1];
  float ss = v0.x*v0.x + v0.y*v0.y + v0.z*v0.z + v0.w*v0.w
           + v1.x*v1.x + v1.y*v1.y + v1.z*v1.z + v1.w*v1.w;
  #pragma unroll
  for (int off = 32; off >= 1; off >>= 1) ss += __shfl_xor(ss, off, 64);
  float inv = 1.0f / fmaxf(sqrtf(ss), 1e-12f);
  int p0 = __builtin_amdgcn_cvt_pk_fp8_f32(v0.x * inv, v0.y * inv, 0, false);
  p0     = __builtin_amdgcn_cvt_pk_fp8_f32(v0.z * inv, v0.w * inv, p0, true);
  int p1 = __builtin_amdgcn_cvt_pk_fp8_f32(v1.x * inv, v1.y * inv, 0, false);
  p1     = __builtin_amdgcn_cvt_pk_fp8_f32(v1.z * inv, v1.w * inv, p1, true);
  ((int2*)dst)[lane] = make_int2(p0, p1);
}

// ---------- kernel 2: fp8 GEMM (nx @ nW^T) -- the R0 87-us structure, atomics removed ----------
// R17: six falsified alternatives (R1/R2 phase schedules, R3 fusion, R4 counted-vmcnt,
// R5/R6 MX-scaled MFMA) all lost to this 2-barrier dbuf 128^2 structure; restored
// byte-identical. One counter was never explained: WRITE_SIZE ~16 MB for 16 KB of
// output = 512K rowsum atomicAdds x 32 B write-through + L2 RMW serialization on 512
// hot lines. Each (row, ct, wn) partial is produced EXACTLY once, so atomics are
// unnecessary: plain-store to part[row][2*ct+wn] (2048 x 500 f32 = 4 MB ws); the
// finish kernel sums 500 contiguous floats per row. Same additions, same tolerance
// (atomic order was already nondeterministic with absmax 0).
__global__ __launch_bounds__(256, 4)
void arc_gemm_kernel(const uint8_t* __restrict__ nx,
                     const uint8_t* __restrict__ nw,
                     const int* __restrict__ labels,
                     float* __restrict__ part,
                     float* __restrict__ lbl_logit) {
  __shared__ uint8_t sA[2][BM * BK];   // 2 x 8 KB
  __shared__ uint8_t sB[2][BN * BK];   // 2 x 8 KB

  const int id = blockIdx.x;
  const int ct = ((id >> 7) << 3) | (id & 7);
  if (ct >= NCT) return;
  const int rt = (id >> 3) & 15;
  const int m0 = rt * BM;
  const int n0 = ct * BN;

  const int tid  = threadIdx.x;
  const int wave = tid >> 6;
  const int lane = tid & 63;
  const int wm   = wave >> 1;
  const int wn   = wave & 1;
  const int quad = lane >> 4;
  const int l16  = lane & 15;

  // staging: inst i covers rows i*64 + (tid>>2); slot tid&3 <- global 16B chunk jg.
  const int srow = tid >> 2;
  const int jg   = (tid & 3) ^ ((srow >> 1) & 3);
  const uint8_t* gA = nx + (size_t)(m0 + srow) * D_DIM + jg * 16;
  const uint8_t* gB = nw + (size_t)(n0 + srow) * D_DIM + jg * 16;
  const int ldsOff0 = wave * 1024;          // wave-uniform LDS byte bases
  const int ldsOff1 = 4096 + wave * 1024;

  // frag reads: row stride 64 B, 16B slot XOR swizzle (measured-zero-conflict math)
  const int cSlot = (quad ^ ((l16 >> 1) & 3)) << 4;
  const int aBase = (wm * 64 + l16) * BK + cSlot;   // + mi*16*BK
  const int bBase = (wn * 64 + l16) * BK + cSlot;   // + ni*16*BK

  f32x4 acc[4][4];
  #pragma unroll
  for (int i = 0; i < 4; ++i)
    #pragma unroll
    for (int j = 0; j < 4; ++j) acc[i][j] = (f32x4){0.f, 0.f, 0.f, 0.f};

  // prologue: tile 0 -> buf 0
  load16_to_lds(gA,              &sA[0][ldsOff0]);
  load16_to_lds(gA + 64 * D_DIM, &sA[0][ldsOff1]);
  load16_to_lds(gB,              &sB[0][ldsOff0]);
  load16_to_lds(gB + 64 * D_DIM, &sB[0][ldsOff1]);

  #pragma unroll
  for (int ks = 0; ks < KSTEPS; ++ks) {
    __syncthreads();                          // prev compute done before overwrite
    if (ks + 1 < KSTEPS) {
      const int off = (ks + 1) * BK;
      const int nb  = (ks + 1) & 1;
      load16_to_lds(gA + off,              &sA[nb][ldsOff0]);
      load16_to_lds(gA + 64 * D_DIM + off, &sA[nb][ldsOff1]);
      load16_to_lds(gB + off,              &sB[nb][ldsOff0]);
      load16_to_lds(gB + 64 * D_DIM + off, &sB[nb][ldsOff1]);
    }
    __syncthreads();                          // tile ks resident

    const uint8_t* bA = sA[ks & 1];
    const uint8_t* bB = sB[ks & 1];
    i64x2 a2[4];
    #pragma unroll
    for (int mi = 0; mi < 4; ++mi)
      a2[mi] = *(const i64x2*)(bA + aBase + mi * 16 * BK);
    #pragma unroll
    for (int ni = 0; ni < 4; ++ni) {
      const i64x2 b2 = *(const i64x2*)(bB + bBase + ni * 16 * BK);
      #pragma unroll
      for (int mi = 0; mi < 4; ++mi) {
        acc[mi][ni] = __builtin_amdgcn_mfma_f32_16x16x32_fp8_fp8(a2[mi][0], b2[0], acc[mi][ni], 0, 0, 0);
        acc[mi][ni] = __builtin_amdgcn_mfma_f32_16x16x32_fp8_fp8(a2[mi][1], b2[1], acc[mi][ni], 0, 0, 0);
      }
    }
  }

  // Epilogue (R4-proven math). C/D layout: col = lane&15, row = quad*4 + reg.
  const int lblv = labels[m0 + wm * 64 + lane];
  const int pcol = (ct << 1) | wn;            // 0..499, block/wave-uniform
  #pragma unroll
  for (int mi = 0; mi < 4; ++mi) {
    #pragma unroll
    for (int r = 0; r < 4; ++r) {
      const int rw   = mi * 16 + quad * 4 + r;
      const int grow = m0 + wm * 64 + rw;
      const int lbl  = __shfl(lblv, rw, 64);
      float rsum = 0.f;
      #pragma unroll
      for (int ni = 0; ni < 4; ++ni) {
        float c = acc[mi][ni][r];
        const int gcol = n0 + wn * 64 + ni * 16 + l16;
        if (gcol == lbl) {
          float sy  = sqrtf(fminf(1.f, fmaxf(0.f, 1.f - c * c)));
          float phi = c * COS_M - sy * SIN_M;
          lbl_logit[grow] = S_SC * phi;       // exactly one lane grid-wide
          c = phi;
        }
        rsum += __expf(S_SC * c - 30.0f);     // fixed shift: logits in [-30,30]
      }
      #pragma unroll
      for (int off = 1; off < 16; off <<= 1)
        rsum += __shfl_xor(rsum, off, 64);
      if (l16 == 0) part[((size_t)grow << 9) + pcol] = rsum;   // plain store, no RMW
    }
  }
}

// ---------- kernel 3: per-row partial reduce + loss + global mean ----------
__global__ void arc_finish_kernel(const float* __restrict__ part,
                                  const float* __restrict__ lbl_logit,
                                  float* __restrict__ out) {
  const int row  = blockIdx.x * 256 + threadIdx.x;   // 8 blocks x 256
  const int lane = threadIdx.x & 63;
  const int wave = threadIdx.x >> 6;
  const float4* p4 = (const float4*)(part + ((size_t)row << 9));
  float s0 = 0.f, s1 = 0.f, s2 = 0.f, s3 = 0.f;
  #pragma unroll
  for (int i = 0; i < 125; ++i) {             // 125 x 4 = 500 partials exactly
    float4 q = p4[i];
    s0 += q.x; s1 += q.y; s2 += q.z; s3 += q.w;
  }
  float rowsum = (s0 + s1) + (s2 + s3);
  float v = (30.0f + logf(rowsum) - lbl_logit[row]) * (1.0f / (float)B_ROWS);
  #pragma unroll
  for (int off = 32; off >= 1; off >>= 1) v += __shfl_xor(v, off, 64);
  __shared__ float wsum[4];
  if (lane == 0) wsum[wave] = v;
  __syncthreads();
  if (threadIdx.x == 0) atomicAdd(out, wsum[0] + wsum[1] + wsum[2] + wsum[3]);
}

// ---------- launch ----------
extern "C" void kernel_launch(void* const* d_in, const int* in_sizes, int n_in,
                              void* d_out, int out_size, void* d_ws, size_t ws_size,
                              hipStream_t stream) {
  const float* x      = (const float*)d_in[0];
  const float* W      = (const float*)d_in[1];
  const int*   labels = (const int*)d_in[2];
  float* out = (float*)d_out;

  char* ws = (char*)d_ws;
  uint8_t* nx = (uint8_t*)ws;                                       // 1 MB
  uint8_t* nw = (uint8_t*)(ws + (size_t)B_ROWS * D_DIM);            // 16.4 MB
  char* p = ws + (size_t)B_ROWS * D_DIM + (size_t)V_COLS * D_DIM;
  float* lbl_logit = (float*)p;  p += (size_t)B_ROWS * 4;           // 8 KB
  float* part      = (float*)p;                                     // 2048 x 512 f32 = 4 MB

  hipLaunchKernelGGL(fused_norm_kernel, dim3((B_ROWS + V_COLS) / 4), dim3(256), 0, stream,
                     x, W, nx, nw, out);
  hipLaunchKernelGGL(arc_gemm_kernel, dim3(32 * 16 * 8), dim3(256), 0, stream,
                     nx, nw, labels, part, lbl_logit);
  hipLaunchKernelGGL(arc_finish_kernel, dim3(B_ROWS / 256), dim3(256), 0, stream,
                     part, lbl_logit, out);
}

// Round 9
// 165.003 us; speedup vs baseline: 1.7889x; 1.0725x over previous
//
#include <hip/hip_runtime.h>
#include <math.h>
#include <stdint.h>

#define B_ROWS 2048
#define D_DIM  512
#define V_COLS 32000
#define BM 128
#define BN 128
#define BK 64
#define KSTEPS (D_DIM / BK)             // 8
#define NCT    (V_COLS / BN)            // 250 col tiles
#define S_SC   30.0f
#define COS_M  0.8775825618903728f      // cos(0.5)
#define SIN_M  0.479425538604203f       // sin(0.5)

typedef float f32x4 __attribute__((ext_vector_type(4)));
typedef long  i64x2 __attribute__((ext_vector_type(2)));

__device__ __forceinline__ void load16_to_lds(const void* g, void* l) {
  __builtin_amdgcn_global_load_lds(
      (__attribute__((address_space(1))) void*)(g),
      (__attribute__((address_space(3))) void*)(l),
      16, 0, 0);
}

// ---------- kernel 1: fused row L2-normalize (x,W) fp32 -> fp8 e4m3, + zero out ----------
__global__ void fused_norm_kernel(const float* __restrict__ x,
                                  const float* __restrict__ W,
                                  uint8_t* __restrict__ nx,
                                  uint8_t* __restrict__ nw,
                                  float* __restrict__ out) {
  if (blockIdx.x == 0 && threadIdx.x == 0) out[0] = 0.f;
  const int lane = threadIdx.x & 63;
  const int wave = threadIdx.x >> 6;
  const int gr   = blockIdx.x * 4 + wave;
  const float* src;
  uint8_t* dst;
  if (gr < B_ROWS) {
    src = x + (size_t)gr * D_DIM;
    dst = nx + (size_t)gr * D_DIM;
  } else {
    src = W + (size_t)(gr - B_ROWS) * D_DIM;
    dst = nw + (size_t)(gr - B_ROWS) * D_DIM;
  }
  const float4* r4 = (const float4*)src;
  float4 v0 = r4[2 * lane];
  float4 v1 = r4[2 * lane + 1];
  float ss = v0.x*v0.x + v0.y*v0.y + v0.z*v0.z + v0.w*v0.w
           + v1.x*v1.x + v1.y*v1.y + v1.z*v1.z + v1.w*v1.w;
  #pragma unroll
  for (int off = 32; off >= 1; off >>= 1) ss += __shfl_xor(ss, off, 64);
  float inv = 1.0f / fmaxf(sqrtf(ss), 1e-12f);
  int p0 = __builtin_amdgcn_cvt_pk_fp8_f32(v0.x * inv, v0.y * inv, 0, false);
  p0     = __builtin_amdgcn_cvt_pk_fp8_f32(v0.z * inv, v0.w * inv, p0, true);
  int p1 = __builtin_amdgcn_cvt_pk_fp8_f32(v1.x * inv, v1.y * inv, 0, false);
  p1     = __builtin_amdgcn_cvt_pk_fp8_f32(v1.z * inv, v1.w * inv, p1, true);
  ((int2*)dst)[lane] = make_int2(p0, p1);
}

// ---------- kernel 2: fp8 GEMM (nx @ nW^T) -- R0 structure + plain-store partials ----------
// R19 = R18 resubmitted verbatim (R18's bench was an infra failure: "container failed
// twice" -- no compile/correctness signal). R17 post-mortem: atomic->plain-store cut
// the GEMM 87 -> 73 us (MfmaUtil 31 -> 38.5%) via removing L2 RMW serialization at
// the tail -- NOT via HBM write volume (WRITE_SIZE stayed ~16 MB: write-through
// granularity dominates 4B scattered stores either way). This structure has survived
// seven falsification attempts (R1/R2 phase schedules, R3 fusion, R4 counted-vmcnt,
// R5/R6 MX) and runs at ~920 TF fp8 = the m145-class ceiling for the 2-barrier
// 128^2 loop.
__global__ __launch_bounds__(256, 4)
void arc_gemm_kernel(const uint8_t* __restrict__ nx,
                     const uint8_t* __restrict__ nw,
                     const int* __restrict__ labels,
                     float* __restrict__ part,
                     float* __restrict__ lbl_logit) {
  __shared__ uint8_t sA[2][BM * BK];   // 2 x 8 KB
  __shared__ uint8_t sB[2][BN * BK];   // 2 x 8 KB

  const int id = blockIdx.x;
  const int ct = ((id >> 7) << 3) | (id & 7);
  if (ct >= NCT) return;
  const int rt = (id >> 3) & 15;
  const int m0 = rt * BM;
  const int n0 = ct * BN;

  const int tid  = threadIdx.x;
  const int wave = tid >> 6;
  const int lane = tid & 63;
  const int wm   = wave >> 1;
  const int wn   = wave & 1;
  const int quad = lane >> 4;
  const int l16  = lane & 15;

  // staging: inst i covers rows i*64 + (tid>>2); slot tid&3 <- global 16B chunk jg.
  const int srow = tid >> 2;
  const int jg   = (tid & 3) ^ ((srow >> 1) & 3);
  const uint8_t* gA = nx + (size_t)(m0 + srow) * D_DIM + jg * 16;
  const uint8_t* gB = nw + (size_t)(n0 + srow) * D_DIM + jg * 16;
  const int ldsOff0 = wave * 1024;          // wave-uniform LDS byte bases
  const int ldsOff1 = 4096 + wave * 1024;

  // frag reads: row stride 64 B, 16B slot XOR swizzle (measured-zero-conflict math)
  const int cSlot = (quad ^ ((l16 >> 1) & 3)) << 4;
  const int aBase = (wm * 64 + l16) * BK + cSlot;   // + mi*16*BK
  const int bBase = (wn * 64 + l16) * BK + cSlot;   // + ni*16*BK

  f32x4 acc[4][4];
  #pragma unroll
  for (int i = 0; i < 4; ++i)
    #pragma unroll
    for (int j = 0; j < 4; ++j) acc[i][j] = (f32x4){0.f, 0.f, 0.f, 0.f};

  // prologue: tile 0 -> buf 0
  load16_to_lds(gA,              &sA[0][ldsOff0]);
  load16_to_lds(gA + 64 * D_DIM, &sA[0][ldsOff1]);
  load16_to_lds(gB,              &sB[0][ldsOff0]);
  load16_to_lds(gB + 64 * D_DIM, &sB[0][ldsOff1]);

  #pragma unroll
  for (int ks = 0; ks < KSTEPS; ++ks) {
    __syncthreads();                          // prev compute done before overwrite
    if (ks + 1 < KSTEPS) {
      const int off = (ks + 1) * BK;
      const int nb  = (ks + 1) & 1;
      load16_to_lds(gA + off,              &sA[nb][ldsOff0]);
      load16_to_lds(gA + 64 * D_DIM + off, &sA[nb][ldsOff1]);
      load16_to_lds(gB + off,              &sB[nb][ldsOff0]);
      load16_to_lds(gB + 64 * D_DIM + off, &sB[nb][ldsOff1]);
    }
    __syncthreads();                          // tile ks resident

    const uint8_t* bA = sA[ks & 1];
    const uint8_t* bB = sB[ks & 1];
    i64x2 a2[4];
    #pragma unroll
    for (int mi = 0; mi < 4; ++mi)
      a2[mi] = *(const i64x2*)(bA + aBase + mi * 16 * BK);
    #pragma unroll
    for (int ni = 0; ni < 4; ++ni) {
      const i64x2 b2 = *(const i64x2*)(bB + bBase + ni * 16 * BK);
      #pragma unroll
      for (int mi = 0; mi < 4; ++mi) {
        acc[mi][ni] = __builtin_amdgcn_mfma_f32_16x16x32_fp8_fp8(a2[mi][0], b2[0], acc[mi][ni], 0, 0, 0);
        acc[mi][ni] = __builtin_amdgcn_mfma_f32_16x16x32_fp8_fp8(a2[mi][1], b2[1], acc[mi][ni], 0, 0, 0);
      }
    }
  }

  // Epilogue (R4-proven math). C/D layout: col = lane&15, row = quad*4 + reg.
  const int lblv = labels[m0 + wm * 64 + lane];
  const int pcol = (ct << 1) | wn;            // 0..499, block/wave-uniform
  #pragma unroll
  for (int mi = 0; mi < 4; ++mi) {
    #pragma unroll
    for (int r = 0; r < 4; ++r) {
      const int rw   = mi * 16 + quad * 4 + r;
      const int grow = m0 + wm * 64 + rw;
      const int lbl  = __shfl(lblv, rw, 64);
      float rsum = 0.f;
      #pragma unroll
      for (int ni = 0; ni < 4; ++ni) {
        float c = acc[mi][ni][r];
        const int gcol = n0 + wn * 64 + ni * 16 + l16;
        if (gcol == lbl) {
          float sy  = sqrtf(fminf(1.f, fmaxf(0.f, 1.f - c * c)));
          float phi = c * COS_M - sy * SIN_M;
          lbl_logit[grow] = S_SC * phi;       // exactly one lane grid-wide
          c = phi;
        }
        rsum += __expf(S_SC * c - 30.0f);     // fixed shift: logits in [-30,30]
      }
      #pragma unroll
      for (int off = 1; off < 16; off <<= 1)
        rsum += __shfl_xor(rsum, off, 64);
      if (l16 == 0) part[((size_t)grow << 9) + pcol] = rsum;   // plain store, no RMW
    }
  }
}

// ---------- kernel 3: per-row partial reduce + loss + global mean ----------
// R17's finish used 8 blocks with each thread serially reading 2 KB -- a
// latency-bound ~17 us tail that ate the GEMM win. Now one WAVE per row
// (512 blocks x 4 waves = 2048 waves): lanes read the row's 125 float4 coalesced
// (lane -> p4[lane], and p4[64+lane] for lane<61), shfl_xor reduce. 4 MB at full
// device parallelism ~= 2-3 us.
__global__ void arc_finish_kernel(const float* __restrict__ part,
                                  const float* __restrict__ lbl_logit,
                                  float* __restrict__ out) {
  const int tid  = threadIdx.x;
  const int lane = tid & 63;
  const int wave = tid >> 6;
  const int row  = blockIdx.x * 4 + wave;     // 512 blocks x 4 waves = 2048 rows
  const float4* p4 = (const float4*)(part + ((size_t)row << 9));
  float4 q0 = p4[lane];                       // entries 0..63
  float s = (q0.x + q0.y) + (q0.z + q0.w);
  if (lane < 61) {                            // entries 64..124 (125 total = 500 floats)
    float4 q1 = p4[64 + lane];
    s += (q1.x + q1.y) + (q1.z + q1.w);
  }
  #pragma unroll
  for (int off = 32; off >= 1; off >>= 1) s += __shfl_xor(s, off, 64);
  __shared__ float wsum[4];
  if (lane == 0)
    wsum[wave] = (30.0f + logf(s) - lbl_logit[row]) * (1.0f / (float)B_ROWS);
  __syncthreads();
  if (tid == 0) atomicAdd(out, wsum[0] + wsum[1] + wsum[2] + wsum[3]);
}

// ---------- launch ----------
extern "C" void kernel_launch(void* const* d_in, const int* in_sizes, int n_in,
                              void* d_out, int out_size, void* d_ws, size_t ws_size,
                              hipStream_t stream) {
  const float* x      = (const float*)d_in[0];
  const float* W      = (const float*)d_in[1];
  const int*   labels = (const int*)d_in[2];
  float* out = (float*)d_out;

  char* ws = (char*)d_ws;
  uint8_t* nx = (uint8_t*)ws;                                       // 1 MB
  uint8_t* nw = (uint8_t*)(ws + (size_t)B_ROWS * D_DIM);            // 16.4 MB
  char* p = ws + (size_t)B_ROWS * D_DIM + (size_t)V_COLS * D_DIM;
  float* lbl_logit = (float*)p;  p += (size_t)B_ROWS * 4;           // 8 KB
  float* part      = (float*)p;                                     // 2048 x 512 f32 = 4 MB

  hipLaunchKernelGGL(fused_norm_kernel, dim3((B_ROWS + V_COLS) / 4), dim3(256), 0, stream,
                     x, W, nx, nw, out);
  hipLaunchKernelGGL(arc_gemm_kernel, dim3(32 * 16 * 8), dim3(256), 0, stream,
                     nx, nw, labels, part, lbl_logit);
  hipLaunchKernelGGL(arc_finish_kernel, dim3(B_ROWS / 4), dim3(256), 0, stream,
                     part, lbl_logit, out);
}